// Round 9
// baseline (137.016 us; speedup 1.0000x reference)
//
#include <hip/hip_runtime.h>
#include <hip/hip_bf16.h>
#include <stdint.h>

// Fused causal self-attention, B=2 T=2048 C=1024 H=16 D=64, bf16 MFMA compute.
// Pipeline: prep (x->bf16 + w transposes) | fused QKV GEMM (writes Q,K,V^T) |
//           flash attention (kv-parity split, 1024 co-resident blocks, LDS dbuf,
//           swapped QK^T) | combine partials (into dead Q slot) | out projection.

typedef __attribute__((ext_vector_type(8))) short bf16x8;   // MFMA A/B frag (8 bf16)
typedef __attribute__((ext_vector_type(4))) float f32x4;    // MFMA C/D frag
typedef __attribute__((ext_vector_type(4))) short short4v;

#define MFMA16(a,b,c) __builtin_amdgcn_mfma_f32_16x16x32_bf16(a,b,c,0,0,0)

__device__ __forceinline__ unsigned short f2bfu(float f){
  union { __hip_bfloat16 h; unsigned short u; } cv;
  cv.h = __float2bfloat16(f);
  return cv.u;
}
__device__ __forceinline__ float bfu2f(unsigned short u){
  union { unsigned v; float f; } cv;
  cv.v = ((unsigned)u) << 16;
  return cv.f;
}

// packed f32x2 -> bf16x2 (low = a, high = b), single HW instruction (RNE)
__device__ __forceinline__ unsigned cvtpk(float a, float b){
  unsigned r;
  asm("v_cvt_pk_bf16_f32 %0, %1, %2" : "=v"(r) : "v"(a), "v"(b));
  return r;
}

__device__ __forceinline__ void async16(const void* g, void* s){
  __builtin_amdgcn_global_load_lds((const __attribute__((address_space(1))) void*)g,
                                   (__attribute__((address_space(3))) void*)s, 16, 0, 0);
}

// ---------------- fused prep ----------------
__global__ __launch_bounds__(256)
void prep_k(const float* __restrict__ x, unsigned short* __restrict__ xb,
            const float* __restrict__ wq, const float* __restrict__ wk,
            const float* __restrict__ wv, const float* __restrict__ wp,
            unsigned short* __restrict__ wqkvT, unsigned short* __restrict__ wpT)
{
  __shared__ float t[32][33];
  const int bx = blockIdx.x;
  const int tid = threadIdx.x;
  if (bx < 4096) {
    const int i = bx * 256 + tid;
    const float4 v = ((const float4*)x)[i];
    short4v o;
    o.x = (short)f2bfu(v.x); o.y = (short)f2bfu(v.y);
    o.z = (short)f2bfu(v.z); o.w = (short)f2bfu(v.w);
    ((short4v*)xb)[i] = o;
    return;
  }
  const int b = bx - 4096;
  const int wsel = b >> 10;
  const float* W = (wsel == 0) ? wq : (wsel == 1) ? wk : (wsel == 2) ? wv : wp;
  unsigned short* Wt = (wsel == 3) ? wpT : wqkvT + (size_t)wsel * 1024 * 1024;
  const int bc = ((b & 1023) & 31) * 32;   // col tile
  const int br = ((b & 1023) >> 5) * 32;   // row tile
  const int tx = tid & 31, ty = tid >> 5;  // 32 x 8
  #pragma unroll
  for (int i = 0; i < 32; i += 8)
    t[ty + i][tx] = W[(size_t)(br + ty + i) * 1024 + bc + tx];
  __syncthreads();
  #pragma unroll
  for (int i = 0; i < 32; i += 8)
    Wt[(size_t)(bc + ty + i) * 1024 + br + tx] = f2bfu(t[tx][ty + i]);
}

// ---------------- GEMM: C[M][N] = A[M][1024] * Bt[N][1024]^T ----------------
template<int MODE>
__global__ __launch_bounds__(256)
void gemm_bt(const unsigned short* __restrict__ A, const unsigned short* __restrict__ Bt,
             const float* __restrict__ b0, const float* __restrict__ b1, const float* __restrict__ b2,
             unsigned short* __restrict__ Qo, unsigned short* __restrict__ Ko,
             unsigned short* __restrict__ Vo, float* __restrict__ Fo, int N)
{
  constexpr int K = 1024;
  __shared__ unsigned short As[128 * 32];
  __shared__ unsigned short Bs[128 * 32];
  const int tid = threadIdx.x;
  const int lane = tid & 63;
  const int w = tid >> 6;
  const int l15 = lane & 15, lhi = lane >> 4;
  const int row0 = blockIdx.y * 128;
  const int col0 = blockIdx.x * 128;
  const int wr = (w >> 1) * 64;
  const int wc = (w & 1) * 64;

  f32x4 acc[4][4];
  #pragma unroll
  for (int i = 0; i < 4; i++)
    #pragma unroll
    for (int j = 0; j < 4; j++) acc[i][j] = 0.0f;

  const int srow = lane >> 2;          // 0..15
  const int scol = (lane & 3) * 8;     // elem offset
  const unsigned short* Ab = A  + (size_t)(row0 + w * 32 + srow) * K + scol;
  const unsigned short* Bb = Bt + (size_t)(col0 + w * 32 + srow) * K + scol;
  unsigned short* AsW = As + (w * 32) * 32;   // wave-uniform LDS base
  unsigned short* BsW = Bs + (w * 32) * 32;

  for (int k0 = 0; k0 < K; k0 += 32) {
    __syncthreads();
    async16(Ab + k0,          AsW);
    async16(Ab + k0 + 16 * K, AsW + 16 * 32);
    async16(Bb + k0,          BsW);
    async16(Bb + k0 + 16 * K, BsW + 16 * 32);
    __syncthreads();
    bf16x8 af[4], bfv[4];
    #pragma unroll
    for (int i = 0; i < 4; i++) {
      af[i]  = *(const bf16x8*)&As[(wr + i * 16 + l15) * 32 + lhi * 8];
      bfv[i] = *(const bf16x8*)&Bs[(wc + i * 16 + l15) * 32 + lhi * 8];
    }
    #pragma unroll
    for (int i = 0; i < 4; i++)
      #pragma unroll
      for (int j = 0; j < 4; j++)
        acc[i][j] = MFMA16(af[i], bfv[j], acc[i][j]);
  }

  #pragma unroll
  for (int j = 0; j < 4; j++) {
    const int n = col0 + wc + j * 16 + l15;
    if constexpr (MODE == 0) {
      const int which = n >> 10;
      const int cn = n & 1023;
      const float bias = (which == 0 ? b0[cn] : which == 1 ? b1[cn] : b2[cn]);
      const int h = cn >> 6, d = cn & 63;
      if (which == 2) {
        // V^T: VT[bh][d][t], 4 consecutive t per lane -> one 8B store
        #pragma unroll
        for (int i = 0; i < 4; i++) {
          const int m = row0 + wr + i * 16 + lhi * 4;
          const int b_ = m >> 11, t = m & 2047;
          uint2 pk;
          pk.x = cvtpk(acc[i][j][0] + bias, acc[i][j][1] + bias);
          pk.y = cvtpk(acc[i][j][2] + bias, acc[i][j][3] + bias);
          *(uint2*)(Vo + (((size_t)(b_ * 16 + h) * 64 + d) * 2048 + t)) = pk;
        }
      } else {
        unsigned short* dst = (which == 0 ? Qo : Ko);
        // Q carries 1/sqrt(D) * log2(e) so attention can use exp2 directly
        const float sc = (which == 0 ? 0.125f * 1.44269504f : 1.0f);
        #pragma unroll
        for (int i = 0; i < 4; i++)
          #pragma unroll
          for (int r = 0; r < 4; r++) {
            const int m = row0 + wr + i * 16 + lhi * 4 + r;
            const int b_ = m >> 11, t = m & 2047;
            dst[(((size_t)(b_ * 16 + h) * 2048 + t) * 64) + d] =
                f2bfu((acc[i][j][r] + bias) * sc);
          }
      }
    } else {
      const float bias = b0[n];
      #pragma unroll
      for (int i = 0; i < 4; i++)
        #pragma unroll
        for (int r = 0; r < 4; r++) {
          const int m = row0 + wr + i * 16 + lhi * 4 + r;
          Fo[(size_t)m * N + n] = acc[i][j][r] + bias;
        }
    }
  }
}

// ---------------- flash attention (kv-parity split) ----------------
// grid (16, 32, 2): block (bx, bh, e) processes kv tiles {e, e+2, ...} for the
// 4 q-tile pairs (bx*4+w, 127-bx*4-w). 1024 blocks, 40KB LDS -> 4 blocks/CU,
// all co-resident, 4 waves/SIMD. Each parity emits a normalized partial
// (O/l bf16 + per-row m,l) merged by combine_k.

__device__ __forceinline__ void softmax_pack(
    f32x4 (&s)[4], f32x4 (&o)[4], float& mrun, float& lrun,
    unsigned short* __restrict__ Pw, int l15, int lhi, int q0, int kv0, bool mask)
{
  if (mask) {
    const int q = q0 + l15;
    #pragma unroll
    for (int nf = 0; nf < 4; ++nf)
      #pragma unroll
      for (int r = 0; r < 4; r++) {
        const int kv = kv0 + nf * 16 + lhi * 4 + r;
        if (kv > q) s[nf][r] = -1e30f;
      }
  }
  float m0 = fmaxf(fmaxf(s[0][0], s[0][1]), fmaxf(s[0][2], s[0][3]));
  float m1 = fmaxf(fmaxf(s[1][0], s[1][1]), fmaxf(s[1][2], s[1][3]));
  float m2 = fmaxf(fmaxf(s[2][0], s[2][1]), fmaxf(s[2][2], s[2][3]));
  float m3 = fmaxf(fmaxf(s[3][0], s[3][1]), fmaxf(s[3][2], s[3][3]));
  float pm = fmaxf(fmaxf(m0, m1), fmaxf(m2, m3));
  pm = fmaxf(pm, __shfl_xor(pm, 16, 64));
  pm = fmaxf(pm, __shfl_xor(pm, 32, 64));

  if (__any((int)(pm > mrun + 8.0f))) {       // deferred rescale (log2 units)
    const float mnew = fmaxf(mrun, pm);
    const float sc = exp2f(mrun - mnew);
    mrun = mnew;
    lrun *= sc;
    float scr[4];
    #pragma unroll
    for (int r = 0; r < 4; r++) scr[r] = __shfl(sc, lhi * 4 + r, 64);
    #pragma unroll
    for (int nf = 0; nf < 4; nf++)
      #pragma unroll
      for (int r = 0; r < 4; r++) o[nf][r] *= scr[r];
  }

  float rs = 0.0f;
  const int swz = (l15 & 7) << 4;
  #pragma unroll
  for (int nf = 0; nf < 4; nf++) {
    float p0 = exp2f(s[nf][0] - mrun);
    float p1 = exp2f(s[nf][1] - mrun);
    float p2 = exp2f(s[nf][2] - mrun);
    float p3 = exp2f(s[nf][3] - mrun);
    rs += (p0 + p1) + (p2 + p3);
    uint2 pk;
    pk.x = cvtpk(p0, p1);
    pk.y = cvtpk(p2, p3);
    *(uint2*)((char*)Pw + ((l15 * 128 + nf * 32 + lhi * 8) ^ swz)) = pk;
  }
  rs += __shfl_xor(rs, 16, 64);
  rs += __shfl_xor(rs, 32, 64);
  lrun += rs;
}

__global__ __launch_bounds__(256)
void attn_k(const unsigned short* __restrict__ Q, const unsigned short* __restrict__ Kg,
            const unsigned short* __restrict__ VT,
            unsigned short* __restrict__ Op0, unsigned short* __restrict__ Op1,
            float* __restrict__ ml0, float* __restrict__ ml1)
{
  __shared__ unsigned short Ks[2][64 * 64];
  __shared__ unsigned short Vs[2][64 * 64];
  __shared__ alignas(16) unsigned short Ps[4][1024];  // per wave, shared B->A
  // XCD-chunked bijective swizzle on (bx,bh); parity from z
  const int flat = blockIdx.y * 16 + blockIdx.x;
  const int u = (flat & 7) * 64 + (flat >> 3);
  const int bx = u & 15, bh = u >> 4;
  const int e = blockIdx.z;
  const int tid = threadIdx.x, lane = tid & 63, w = tid >> 6;
  const int l15 = lane & 15, lhi = lane >> 4;
  const int tA = bx * 4 + w, tB = 127 - tA;   // 16-row q-tile ids
  const int q0A = tA * 16, q0B = tB * 16;
  const int jmA = bx, jmB = 31 - bx;          // block-uniform kv-tile bounds

  unsigned short* Op = e ? Op1 : Op0;
  float* ml = e ? ml1 : ml0;

  const unsigned short* Kbh  = Kg + (size_t)bh * (2048 * 64);
  const unsigned short* VTbh = VT + (size_t)bh * (64 * 2048);
  unsigned short* Pw = &Ps[w][0];

  const unsigned short* QpA = Q + ((size_t)bh * 2048 + q0A + l15) * 64 + lhi * 8;
  const unsigned short* QpB = Q + ((size_t)bh * 2048 + q0B + l15) * 64 + lhi * 8;
  const bf16x8 qfA0 = *(const bf16x8*)(QpA);
  const bf16x8 qfA1 = *(const bf16x8*)(QpA + 32);
  const bf16x8 qfB0 = *(const bf16x8*)(QpB);
  const bf16x8 qfB1 = *(const bf16x8*)(QpB + 32);

  f32x4 oA[4], oB[4];
  #pragma unroll
  for (int nf = 0; nf < 4; nf++) { oA[nf] = 0.0f; oB[nf] = 0.0f; }
  float mA = -1e30f, lA = 0.0f, mB = -1e30f, lB = 0.0f;

  // staging: linear LDS dest, pre-swizzled per-lane global source.
  const int srow = w * 8 + (lane >> 3);                 // + it*32
  const int cole = (((lane & 7) ^ (lane >> 3)) << 3);   // element offset (16B blk)
  const unsigned short* Ksrc = Kbh + (size_t)srow * 64 + cole;
  const unsigned short* Vsrc = VTbh + (size_t)srow * 2048 + cole;

  auto stage = [&](int t, int buf) {
    const int kv0 = t * 64;
    unsigned short* kb = &Ks[buf][w * 512];   // wave-uniform
    unsigned short* vb = &Vs[buf][w * 512];
    #pragma unroll
    for (int it = 0; it < 2; ++it) {
      async16(Ksrc + (size_t)(kv0 + it * 32) * 64, kb + it * 2048);
      async16(Vsrc + (size_t)(it * 32) * 2048 + kv0, vb + it * 2048);
    }
  };

  stage(e, 0);
  __syncthreads();     // drains vmcnt before first compute

  int cur = 0;
  for (int t = e; t <= jmB; t += 2) {
    if (t + 2 <= jmB) stage(t + 2, cur ^ 1);   // prefetch next parity tile
    const int kv0 = t * 64;
    const bool doA = (t <= jmA);
    const unsigned short* Ksb = &Ks[cur][0];
    const unsigned short* Vsb = &Vs[cur][0];

    // QK^T for both q-sets sharing K fragment reads
    f32x4 sB[4], sA[4];
    __builtin_amdgcn_s_setprio(1);
    #pragma unroll
    for (int nf = 0; nf < 4; ++nf) {
      const int rk = nf * 16 + l15;
      const int swzk = (rk & 7) << 4;
      const bf16x8 kf0 = *(const bf16x8*)((const char*)Ksb + ((rk * 128 + lhi * 16) ^ swzk));
      const bf16x8 kf1 = *(const bf16x8*)((const char*)Ksb + ((rk * 128 + 64 + lhi * 16) ^ swzk));
      sB[nf] = 0.0f;
      sB[nf] = MFMA16(kf0, qfB0, sB[nf]);
      sB[nf] = MFMA16(kf1, qfB1, sB[nf]);
      if (doA) {
        sA[nf] = 0.0f;
        sA[nf] = MFMA16(kf0, qfA0, sA[nf]);
        sA[nf] = MFMA16(kf1, qfA1, sA[nf]);
      }
    }
    __builtin_amdgcn_s_setprio(0);

    const int swzp = (l15 & 7) << 4;
    softmax_pack(sB, oB, mB, lB, Pw, l15, lhi, q0B, kv0, t == jmB);
    const bf16x8 pfB0 = *(const bf16x8*)((const char*)Pw + ((l15 * 128 + lhi * 16) ^ swzp));
    const bf16x8 pfB1 = *(const bf16x8*)((const char*)Pw + ((l15 * 128 + 64 + lhi * 16) ^ swzp));
    bf16x8 pfA0, pfA1;
    if (doA) {
      softmax_pack(sA, oA, mA, lA, Pw, l15, lhi, q0A, kv0, t == jmA);
      pfA0 = *(const bf16x8*)((const char*)Pw + ((l15 * 128 + lhi * 16) ^ swzp));
      pfA1 = *(const bf16x8*)((const char*)Pw + ((l15 * 128 + 64 + lhi * 16) ^ swzp));
    }

    // O += P V for both q-sets sharing V fragment reads
    __builtin_amdgcn_s_setprio(1);
    #pragma unroll
    for (int nf = 0; nf < 4; nf++) {
      const int rv = nf * 16 + l15;
      const int swzv = (rv & 7) << 4;
      const bf16x8 vf0 = *(const bf16x8*)((const char*)Vsb + ((rv * 128 + lhi * 16) ^ swzv));
      const bf16x8 vf1 = *(const bf16x8*)((const char*)Vsb + ((rv * 128 + 64 + lhi * 16) ^ swzv));
      oB[nf] = MFMA16(pfB0, vf0, oB[nf]);
      oB[nf] = MFMA16(pfB1, vf1, oB[nf]);
      if (doA) {
        oA[nf] = MFMA16(pfA0, vf0, oA[nf]);
        oA[nf] = MFMA16(pfA1, vf1, oA[nf]);
      }
    }
    __builtin_amdgcn_s_setprio(0);

    __syncthreads();   // prefetch landed (vmcnt drain), buffers free
    cur ^= 1;
  }

  // write normalized partials: Op[(bh*128+t)*16+row][d], ml[(bh*128+t)*16+row]
  auto emit = [&](f32x4 (&o)[4], float m, float l, int t) {
    const float inv = (l > 0.0f) ? 1.0f / l : 0.0f;
    if (lhi == 0) {
      float2 v; v.x = m; v.y = l;
      *(float2*)(ml + ((size_t)(bh * 128 + t) * 16 + l15) * 2) = v;
    }
    float invr[4];
    #pragma unroll
    for (int r = 0; r < 4; r++) invr[r] = __shfl(inv, lhi * 4 + r, 64);
    unsigned short* base = Op + (size_t)(bh * 128 + t) * 1024;
    #pragma unroll
    for (int nf = 0; nf < 4; nf++)
      #pragma unroll
      for (int r = 0; r < 4; r++)
        base[(lhi * 4 + r) * 64 + nf * 16 + l15] = f2bfu(o[nf][r] * invr[r]);
  };
  emit(oA, mA, lA, tA);
  emit(oB, mB, lB, tB);
}

// ---------------- combine partials ----------------
// grid 4096 (= bh*128 + t), 256 threads: thread handles row=tid>>4, 4 cols.
// Writes into a DISTINCT buffer (dead Q slot) -- no aliasing with inputs.
__global__ __launch_bounds__(256)
void combine_k(const unsigned short* __restrict__ O0, const unsigned short* __restrict__ O1,
               const float* __restrict__ ml0, const float* __restrict__ ml1,
               unsigned short* __restrict__ Ob)
{
  const int g = blockIdx.x;
  const int bh = g >> 7, t = g & 127;
  const int b_ = bh >> 4, h = bh & 15;
  const int tid = threadIdx.x;
  const int row = tid >> 4, c4 = (tid & 15) * 4;
  const size_t rbase = (size_t)g * 16 + row;
  const float2 v0 = *(const float2*)(ml0 + rbase * 2);
  const float2 v1 = *(const float2*)(ml1 + rbase * 2);
  const float m = fmaxf(v0.x, v1.x);
  const float w0 = v0.y * exp2f(v0.x - m);
  const float w1 = v1.y * exp2f(v1.x - m);
  const float inv = 1.0f / (w0 + w1);
  const float a0 = w0 * inv, a1 = w1 * inv;
  const short4v p0 = *(const short4v*)(O0 + rbase * 64 + c4);
  const short4v p1 = *(const short4v*)(O1 + rbase * 64 + c4);
  unsigned short* dst = Ob + ((size_t)b_ * 2048 + t * 16 + row) * 1024 + h * 64 + c4;
  short4v o;
  o.x = (short)f2bfu(a0 * bfu2f((unsigned short)p0.x) + a1 * bfu2f((unsigned short)p1.x));
  o.y = (short)f2bfu(a0 * bfu2f((unsigned short)p0.y) + a1 * bfu2f((unsigned short)p1.y));
  o.z = (short)f2bfu(a0 * bfu2f((unsigned short)p0.z) + a1 * bfu2f((unsigned short)p1.z));
  o.w = (short)f2bfu(a0 * bfu2f((unsigned short)p0.w) + a1 * bfu2f((unsigned short)p1.w));
  *(short4v*)dst = o;
}

// ---------------- launch ----------------

extern "C" void kernel_launch(void* const* d_in, const int* in_sizes, int n_in,
                              void* d_out, int out_size, void* d_ws, size_t ws_size,
                              hipStream_t stream) {
  const float* x  = (const float*)d_in[0];
  const float* wq = (const float*)d_in[1];
  const float* bq = (const float*)d_in[2];
  const float* wk = (const float*)d_in[3];
  const float* bk = (const float*)d_in[4];
  const float* wv = (const float*)d_in[5];
  const float* bv = (const float*)d_in[6];
  const float* wp = (const float*)d_in[7];
  const float* bp = (const float*)d_in[8];
  float* out = (float*)d_out;

  char* ws = (char*)d_ws;
  const size_t MB = 1024 * 1024;
  unsigned short* xb    = (unsigned short*)(ws);             // 8MB, dead after QKV
  unsigned short* wqkvT = (unsigned short*)(ws + 8  * MB);   // 6MB, dead after QKV
  unsigned short* wpT   = (unsigned short*)(ws + 14 * MB);   // 2MB (live to the end)
  unsigned short* Qb    = (unsigned short*)(ws + 16 * MB);   // 8MB, dead after attn
  unsigned short* Kb    = (unsigned short*)(ws + 24 * MB);   // 8MB, dead after attn
  unsigned short* VTb   = (unsigned short*)(ws + 32 * MB);   // 8MB, dead after attn
  // attention partials (reusing dead regions + d_out scratch)
  unsigned short* Op0   = (unsigned short*)(ws);             // 8MB, alias xb
  float*          ml0   = (float*)(ws + 8 * MB);             // 512KB, alias wqkvT
  float*          ml1   = (float*)(ws + 8 * MB + 512 * 1024);// 512KB, alias wqkvT
  unsigned short* Op1   = (unsigned short*)d_out;            // 8MB scratch in out buf
  unsigned short* Ob    = Qb;                                // combined O -> dead Q slot

  prep_k<<<dim3(8192), dim3(256), 0, stream>>>(x, xb, wq, wk, wv, wp, wqkvT, wpT);

  gemm_bt<0><<<dim3(24, 32), dim3(256), 0, stream>>>(xb, wqkvT, bq, bk, bv,
                                                     Qb, Kb, VTb, nullptr, 3072);
  attn_k<<<dim3(16, 32, 2), dim3(256), 0, stream>>>(Qb, Kb, VTb, Op0, Op1, ml0, ml1);
  combine_k<<<dim3(4096), dim3(256), 0, stream>>>(Op0, Op1, ml0, ml1, Ob);
  gemm_bt<1><<<dim3(8, 32), dim3(256), 0, stream>>>(Ob, wpT, bp, nullptr, nullptr,
                                                    nullptr, nullptr, nullptr, out, 1024);
}

// Round 10
// 127.174 us; speedup vs baseline: 1.0774x; 1.0774x over previous
//
#include <hip/hip_runtime.h>
#include <hip/hip_bf16.h>
#include <stdint.h>

// Fused causal self-attention, B=2 T=2048 C=1024 H=16 D=64, bf16 MFMA compute.
// Pipeline: prep (x->bf16 + w transposes) | fused QKV GEMM (dbuf K-loop,
//           writes Q,K,V^T) | flash attention (LDS dbuf KV, swapped QK^T,
//           paired q-tiles sharing K/V frag reads, XCD-chunked blocks) |
//           out projection (dbuf K-loop).

typedef __attribute__((ext_vector_type(8))) short bf16x8;   // MFMA A/B frag (8 bf16)
typedef __attribute__((ext_vector_type(4))) float f32x4;    // MFMA C/D frag
typedef __attribute__((ext_vector_type(4))) short short4v;

#define MFMA16(a,b,c) __builtin_amdgcn_mfma_f32_16x16x32_bf16(a,b,c,0,0,0)

__device__ __forceinline__ unsigned short f2bfu(float f){
  union { __hip_bfloat16 h; unsigned short u; } cv;
  cv.h = __float2bfloat16(f);
  return cv.u;
}

// packed f32x2 -> bf16x2 (low = a, high = b), single HW instruction (RNE)
__device__ __forceinline__ unsigned cvtpk(float a, float b){
  unsigned r;
  asm("v_cvt_pk_bf16_f32 %0, %1, %2" : "=v"(r) : "v"(a), "v"(b));
  return r;
}

__device__ __forceinline__ void async16(const void* g, void* s){
  __builtin_amdgcn_global_load_lds((const __attribute__((address_space(1))) void*)g,
                                   (__attribute__((address_space(3))) void*)s, 16, 0, 0);
}

// ---------------- fused prep ----------------
// blocks 0..4095: convert x (fp32->bf16, float4/thread)
// blocks 4096..8191: transpose+convert one 32x32 tile of wq/wk/wv/wp
__global__ __launch_bounds__(256)
void prep_k(const float* __restrict__ x, unsigned short* __restrict__ xb,
            const float* __restrict__ wq, const float* __restrict__ wk,
            const float* __restrict__ wv, const float* __restrict__ wp,
            unsigned short* __restrict__ wqkvT, unsigned short* __restrict__ wpT)
{
  __shared__ float t[32][33];
  const int bx = blockIdx.x;
  const int tid = threadIdx.x;
  if (bx < 4096) {
    const int i = bx * 256 + tid;
    const float4 v = ((const float4*)x)[i];
    short4v o;
    o.x = (short)f2bfu(v.x); o.y = (short)f2bfu(v.y);
    o.z = (short)f2bfu(v.z); o.w = (short)f2bfu(v.w);
    ((short4v*)xb)[i] = o;
    return;
  }
  const int b = bx - 4096;
  const int wsel = b >> 10;
  const float* W = (wsel == 0) ? wq : (wsel == 1) ? wk : (wsel == 2) ? wv : wp;
  unsigned short* Wt = (wsel == 3) ? wpT : wqkvT + (size_t)wsel * 1024 * 1024;
  const int bc = ((b & 1023) & 31) * 32;   // col tile
  const int br = ((b & 1023) >> 5) * 32;   // row tile
  const int tx = tid & 31, ty = tid >> 5;  // 32 x 8
  #pragma unroll
  for (int i = 0; i < 32; i += 8)
    t[ty + i][tx] = W[(size_t)(br + ty + i) * 1024 + bc + tx];
  __syncthreads();
  #pragma unroll
  for (int i = 0; i < 32; i += 8)
    Wt[(size_t)(bc + ty + i) * 1024 + br + tx] = f2bfu(t[tx][ty + i]);
}

// ---------------- GEMM: C[M][N] = A[M][1024] * Bt[N][1024]^T ----------------
// Double-buffered LDS K-loop: prefetch step k+1 via global_load_lds before
// computing step k; one barrier per step (drains prefetch, frees buffers).
// MODE 0: fused QKV (N=3072). Writes Q (scaled 0.125*log2e) and K as
//         [B,H,T,D] bf16, and V TRANSPOSED as VT [B,H,D,T] (packed 8B stores).
// MODE 1: projection (N=1024), writes fp32 + bias to out
template<int MODE>
__global__ __launch_bounds__(256)
void gemm_bt(const unsigned short* __restrict__ A, const unsigned short* __restrict__ Bt,
             const float* __restrict__ b0, const float* __restrict__ b1, const float* __restrict__ b2,
             unsigned short* __restrict__ Qo, unsigned short* __restrict__ Ko,
             unsigned short* __restrict__ Vo, float* __restrict__ Fo, int N)
{
  constexpr int K = 1024;
  __shared__ unsigned short As[2][128 * 32];
  __shared__ unsigned short Bs[2][128 * 32];
  const int tid = threadIdx.x;
  const int lane = tid & 63;
  const int w = tid >> 6;
  const int l15 = lane & 15, lhi = lane >> 4;
  const int row0 = blockIdx.y * 128;
  const int col0 = blockIdx.x * 128;
  const int wr = (w >> 1) * 64;
  const int wc = (w & 1) * 64;

  f32x4 acc[4][4];
  #pragma unroll
  for (int i = 0; i < 4; i++)
    #pragma unroll
    for (int j = 0; j < 4; j++) acc[i][j] = 0.0f;

  const int srow = lane >> 2;          // 0..15
  const int scol = (lane & 3) * 8;     // elem offset
  const unsigned short* Ab = A  + (size_t)(row0 + w * 32 + srow) * K + scol;
  const unsigned short* Bb = Bt + (size_t)(col0 + w * 32 + srow) * K + scol;
  const int wofs = (w * 32) * 32;      // wave-uniform LDS base (elems)

  auto stageg = [&](int k0, int buf) {
    async16(Ab + k0,          &As[buf][wofs]);
    async16(Ab + k0 + 16 * K, &As[buf][wofs + 16 * 32]);
    async16(Bb + k0,          &Bs[buf][wofs]);
    async16(Bb + k0 + 16 * K, &Bs[buf][wofs + 16 * 32]);
  };

  stageg(0, 0);
  __syncthreads();               // drain first stage
  int cur = 0;
  for (int k0 = 0; k0 < K; k0 += 32) {
    if (k0 + 32 < K) stageg(k0 + 32, cur ^ 1);   // prefetch next K-step
    bf16x8 af[4], bfv[4];
    #pragma unroll
    for (int i = 0; i < 4; i++) {
      af[i]  = *(const bf16x8*)&As[cur][(wr + i * 16 + l15) * 32 + lhi * 8];
      bfv[i] = *(const bf16x8*)&Bs[cur][(wc + i * 16 + l15) * 32 + lhi * 8];
    }
    __builtin_amdgcn_s_setprio(1);
    #pragma unroll
    for (int i = 0; i < 4; i++)
      #pragma unroll
      for (int j = 0; j < 4; j++)
        acc[i][j] = MFMA16(af[i], bfv[j], acc[i][j]);
    __builtin_amdgcn_s_setprio(0);
    __syncthreads();             // prefetch landed; old buffer free
    cur ^= 1;
  }

  #pragma unroll
  for (int j = 0; j < 4; j++) {
    const int n = col0 + wc + j * 16 + l15;
    if constexpr (MODE == 0) {
      const int which = n >> 10;     // uniform per j (16-span inside 64-block)
      const int cn = n & 1023;
      const float bias = (which == 0 ? b0[cn] : which == 1 ? b1[cn] : b2[cn]);
      const int h = cn >> 6, d = cn & 63;
      if (which == 2) {
        // V^T: VT[bh][d][t], 4 consecutive t per lane -> one 8B store
        #pragma unroll
        for (int i = 0; i < 4; i++) {
          const int m = row0 + wr + i * 16 + lhi * 4;
          const int b_ = m >> 11, t = m & 2047;
          uint2 pk;
          pk.x = cvtpk(acc[i][j][0] + bias, acc[i][j][1] + bias);
          pk.y = cvtpk(acc[i][j][2] + bias, acc[i][j][3] + bias);
          *(uint2*)(Vo + (((size_t)(b_ * 16 + h) * 64 + d) * 2048 + t)) = pk;
        }
      } else {
        unsigned short* dst = (which == 0 ? Qo : Ko);
        // Q carries 1/sqrt(D) * log2(e) so attention can use exp2 directly
        const float sc = (which == 0 ? 0.125f * 1.44269504f : 1.0f);
        #pragma unroll
        for (int i = 0; i < 4; i++)
          #pragma unroll
          for (int r = 0; r < 4; r++) {
            const int m = row0 + wr + i * 16 + lhi * 4 + r;
            const int b_ = m >> 11, t = m & 2047;
            dst[(((size_t)(b_ * 16 + h) * 2048 + t) * 64) + d] =
                f2bfu((acc[i][j][r] + bias) * sc);
          }
      }
    } else {
      const float bias = b0[n];
      #pragma unroll
      for (int i = 0; i < 4; i++)
        #pragma unroll
        for (int r = 0; r < 4; r++) {
          const int m = row0 + wr + i * 16 + lhi * 4 + r;
          Fo[(size_t)m * N + n] = acc[i][j][r] + bias;
        }
    }
  }
}

// ---------------- flash attention ----------------
// grid (16, B*H) remapped via XCD-chunked swizzle. 4 waves/block; wave w owns
// q-tile pair (bx*4+w, 127-bx*4-w). Block-uniform kv loop (jmA=bx, jmB=31-bx).
// K/V staged in dbuf LDS (global_load_lds, pre-swizzled source). Swapped QK^T:
// lane q=q0+l15; per-lane scalar (m,l). A and B share the K/V fragment reads.

__device__ __forceinline__ void softmax_pack(
    f32x4 (&s)[4], f32x4 (&o)[4], float& mrun, float& lrun,
    unsigned short* __restrict__ Pw, int l15, int lhi, int q0, int kv0, bool mask)
{
  if (mask) {
    const int q = q0 + l15;
    #pragma unroll
    for (int nf = 0; nf < 4; ++nf)
      #pragma unroll
      for (int r = 0; r < 4; r++) {
        const int kv = kv0 + nf * 16 + lhi * 4 + r;
        if (kv > q) s[nf][r] = -1e30f;
      }
  }
  float m0 = fmaxf(fmaxf(s[0][0], s[0][1]), fmaxf(s[0][2], s[0][3]));
  float m1 = fmaxf(fmaxf(s[1][0], s[1][1]), fmaxf(s[1][2], s[1][3]));
  float m2 = fmaxf(fmaxf(s[2][0], s[2][1]), fmaxf(s[2][2], s[2][3]));
  float m3 = fmaxf(fmaxf(s[3][0], s[3][1]), fmaxf(s[3][2], s[3][3]));
  float pm = fmaxf(fmaxf(m0, m1), fmaxf(m2, m3));
  pm = fmaxf(pm, __shfl_xor(pm, 16, 64));
  pm = fmaxf(pm, __shfl_xor(pm, 32, 64));

  if (__any((int)(pm > mrun + 8.0f))) {       // deferred rescale (log2 units)
    const float mnew = fmaxf(mrun, pm);
    const float sc = exp2f(mrun - mnew);
    mrun = mnew;
    lrun *= sc;
    float scr[4];
    #pragma unroll
    for (int r = 0; r < 4; r++) scr[r] = __shfl(sc, lhi * 4 + r, 64);
    #pragma unroll
    for (int nf = 0; nf < 4; nf++)
      #pragma unroll
      for (int r = 0; r < 4; r++) o[nf][r] *= scr[r];
  }

  float rs = 0.0f;
  const int swz = (l15 & 7) << 4;
  #pragma unroll
  for (int nf = 0; nf < 4; nf++) {
    float p0 = exp2f(s[nf][0] - mrun);
    float p1 = exp2f(s[nf][1] - mrun);
    float p2 = exp2f(s[nf][2] - mrun);
    float p3 = exp2f(s[nf][3] - mrun);
    rs += (p0 + p1) + (p2 + p3);
    uint2 pk;
    pk.x = cvtpk(p0, p1);
    pk.y = cvtpk(p2, p3);
    *(uint2*)((char*)Pw + ((l15 * 128 + nf * 32 + lhi * 8) ^ swz)) = pk;
  }
  rs += __shfl_xor(rs, 16, 64);
  rs += __shfl_xor(rs, 32, 64);
  lrun += rs;
}

__global__ __launch_bounds__(256)
void attn_k(const unsigned short* __restrict__ Q, const unsigned short* __restrict__ Kg,
            const unsigned short* __restrict__ VT, unsigned short* __restrict__ O)
{
  __shared__ unsigned short Ks[2][64 * 64];
  __shared__ unsigned short Vs[2][64 * 64];
  __shared__ alignas(16) unsigned short Ps[4][2048];  // per wave: [B 1KB][A 1KB]
  // XCD-chunked bijective swizzle (512 blocks, 64 per XCD -> 4 bh per XCD L2)
  const int flat = blockIdx.y * 16 + blockIdx.x;
  const int u = (flat & 7) * 64 + (flat >> 3);
  const int bx = u & 15, bh = u >> 4;
  const int b_ = bh >> 4, h = bh & 15;
  const int tid = threadIdx.x, lane = tid & 63, w = tid >> 6;
  const int l15 = lane & 15, lhi = lane >> 4;
  const int tA = bx * 4 + w, tB = 127 - tA;   // 16-row q-tile ids
  const int q0A = tA * 16, q0B = tB * 16;
  const int jmA = bx, jmB = 31 - bx;          // block-uniform kv-tile bounds

  const unsigned short* Kbh  = Kg + (size_t)bh * (2048 * 64);
  const unsigned short* VTbh = VT + (size_t)bh * (64 * 2048);
  unsigned short* PwB = &Ps[w][0];
  unsigned short* PwA = &Ps[w][1024];

  const unsigned short* QpA = Q + ((size_t)bh * 2048 + q0A + l15) * 64 + lhi * 8;
  const unsigned short* QpB = Q + ((size_t)bh * 2048 + q0B + l15) * 64 + lhi * 8;
  const bf16x8 qfA0 = *(const bf16x8*)(QpA);
  const bf16x8 qfA1 = *(const bf16x8*)(QpA + 32);
  const bf16x8 qfB0 = *(const bf16x8*)(QpB);
  const bf16x8 qfB1 = *(const bf16x8*)(QpB + 32);

  f32x4 oA[4], oB[4];
  #pragma unroll
  for (int nf = 0; nf < 4; nf++) { oA[nf] = 0.0f; oB[nf] = 0.0f; }
  float mA = -1e30f, lA = 0.0f, mB = -1e30f, lB = 0.0f;

  // staging: linear LDS dest (lane*16B per wave quarter), pre-swizzled source.
  // LDS byte b holds (row=b>>7, colbyte=(b&127)^((row&7)<<4)).
  const int srow = w * 8 + (lane >> 3);                 // + it*32
  const int cole = (((lane & 7) ^ (lane >> 3)) << 3);   // element offset (16B blk)
  const unsigned short* Ksrc = Kbh + (size_t)srow * 64 + cole;
  const unsigned short* Vsrc = VTbh + (size_t)srow * 2048 + cole;

  auto stage = [&](int kv0, int buf) {
    unsigned short* kb = &Ks[buf][w * 512];   // w*1024 bytes, wave-uniform
    unsigned short* vb = &Vs[buf][w * 512];
    #pragma unroll
    for (int it = 0; it < 2; ++it) {
      async16(Ksrc + (size_t)(kv0 + it * 32) * 64, kb + it * 2048);
      async16(Vsrc + (size_t)(it * 32) * 2048 + kv0, vb + it * 2048);
    }
  };

  stage(0, 0);
  __syncthreads();     // drains vmcnt before first compute

  int cur = 0;
  for (int j = 0; j <= jmB; ++j) {
    if (j < jmB) stage((j + 1) * 64, cur ^ 1);   // prefetch next tile
    const int kv0 = j * 64;
    const bool doA = (j <= jmA);
    const unsigned short* Ksb = &Ks[cur][0];
    const unsigned short* Vsb = &Vs[cur][0];

    // QK^T for both q-sets sharing K fragment reads
    f32x4 sB[4], sA[4];
    __builtin_amdgcn_s_setprio(1);
    #pragma unroll
    for (int nf = 0; nf < 4; ++nf) {
      const int rk = nf * 16 + l15;
      const int swzk = (rk & 7) << 4;
      const bf16x8 kf0 = *(const bf16x8*)((const char*)Ksb + ((rk * 128 + lhi * 16) ^ swzk));
      const bf16x8 kf1 = *(const bf16x8*)((const char*)Ksb + ((rk * 128 + 64 + lhi * 16) ^ swzk));
      sB[nf] = 0.0f;
      sB[nf] = MFMA16(kf0, qfB0, sB[nf]);
      sB[nf] = MFMA16(kf1, qfB1, sB[nf]);
      if (doA) {
        sA[nf] = 0.0f;
        sA[nf] = MFMA16(kf0, qfA0, sA[nf]);
        sA[nf] = MFMA16(kf1, qfA1, sA[nf]);
      }
    }
    __builtin_amdgcn_s_setprio(0);

    softmax_pack(sB, oB, mB, lB, PwB, l15, lhi, q0B, kv0, j == jmB);
    if (doA) softmax_pack(sA, oA, mA, lA, PwA, l15, lhi, q0A, kv0, j == jmA);

    const int swzp = (l15 & 7) << 4;
    const bf16x8 pfB0 = *(const bf16x8*)((const char*)PwB + ((l15 * 128 + lhi * 16) ^ swzp));
    const bf16x8 pfB1 = *(const bf16x8*)((const char*)PwB + ((l15 * 128 + 64 + lhi * 16) ^ swzp));
    bf16x8 pfA0, pfA1;
    if (doA) {
      pfA0 = *(const bf16x8*)((const char*)PwA + ((l15 * 128 + lhi * 16) ^ swzp));
      pfA1 = *(const bf16x8*)((const char*)PwA + ((l15 * 128 + 64 + lhi * 16) ^ swzp));
    }

    // O += P V for both q-sets sharing V fragment reads
    __builtin_amdgcn_s_setprio(1);
    #pragma unroll
    for (int nf = 0; nf < 4; nf++) {
      const int rv = nf * 16 + l15;
      const int swzv = (rv & 7) << 4;
      const bf16x8 vf0 = *(const bf16x8*)((const char*)Vsb + ((rv * 128 + lhi * 16) ^ swzv));
      const bf16x8 vf1 = *(const bf16x8*)((const char*)Vsb + ((rv * 128 + 64 + lhi * 16) ^ swzv));
      oB[nf] = MFMA16(pfB0, vf0, oB[nf]);
      oB[nf] = MFMA16(pfB1, vf1, oB[nf]);
      if (doA) {
        oA[nf] = MFMA16(pfA0, vf0, oA[nf]);
        oA[nf] = MFMA16(pfA1, vf1, oA[nf]);
      }
    }
    __builtin_amdgcn_s_setprio(0);

    __syncthreads();   // prefetch landed (vmcnt drain), buffers free
    cur ^= 1;
  }

  const float linvA = 1.0f / lA, linvB = 1.0f / lB;
  float invA[4], invB[4];
  #pragma unroll
  for (int r = 0; r < 4; r++) {
    invA[r] = __shfl(linvA, lhi * 4 + r, 64);
    invB[r] = __shfl(linvB, lhi * 4 + r, 64);
  }
  #pragma unroll
  for (int nf = 0; nf < 4; nf++)
    #pragma unroll
    for (int r = 0; r < 4; r++) {
      const int c = h * 64 + nf * 16 + l15;
      O[((size_t)b_ * 2048 + q0A + lhi * 4 + r) * 1024 + c] = f2bfu(oA[nf][r] * invA[r]);
      O[((size_t)b_ * 2048 + q0B + lhi * 4 + r) * 1024 + c] = f2bfu(oB[nf][r] * invB[r]);
    }
}

// ---------------- launch ----------------

extern "C" void kernel_launch(void* const* d_in, const int* in_sizes, int n_in,
                              void* d_out, int out_size, void* d_ws, size_t ws_size,
                              hipStream_t stream) {
  const float* x  = (const float*)d_in[0];
  const float* wq = (const float*)d_in[1];
  const float* bq = (const float*)d_in[2];
  const float* wk = (const float*)d_in[3];
  const float* bk = (const float*)d_in[4];
  const float* wv = (const float*)d_in[5];
  const float* bv = (const float*)d_in[6];
  const float* wp = (const float*)d_in[7];
  const float* bp = (const float*)d_in[8];
  float* out = (float*)d_out;

  char* ws = (char*)d_ws;
  const size_t MB = 1024 * 1024;
  unsigned short* xb    = (unsigned short*)(ws);             // 8MB  [4096][1024]
  unsigned short* wqkvT = (unsigned short*)(ws + 8  * MB);   // 6MB  [3072][1024]
  unsigned short* wpT   = (unsigned short*)(ws + 14 * MB);   // 2MB  [1024][1024]
  unsigned short* Qb    = (unsigned short*)(ws + 16 * MB);   // 8MB  [32][2048][64]
  unsigned short* Kb    = (unsigned short*)(ws + 24 * MB);   // 8MB  [32][2048][64]
  unsigned short* VTb   = (unsigned short*)(ws + 32 * MB);   // 8MB  [32][64][2048]
  unsigned short* Ob    = (unsigned short*)(ws);             // alias xb (dead after QKV GEMM)

  prep_k<<<dim3(8192), dim3(256), 0, stream>>>(x, xb, wq, wk, wv, wp, wqkvT, wpT);

  gemm_bt<0><<<dim3(24, 32), dim3(256), 0, stream>>>(xb, wqkvT, bq, bk, bv,
                                                     Qb, Kb, VTb, nullptr, 3072);
  attn_k<<<dim3(16, 32), dim3(256), 0, stream>>>(Qb, Kb, VTb, Ob);
  gemm_bt<1><<<dim3(8, 32), dim3(256), 0, stream>>>(Ob, wpT, bp, nullptr, nullptr,
                                                    nullptr, nullptr, nullptr, out, 1024);
}